// Round 14
// baseline (428.963 us; speedup 1.0000x reference)
//
#include <hip/hip_runtime.h>
#include <math.h>

#define BB 8
#define TT 4096
#define DDIM 512
#define KK 4096
#define NN (BB*TT)
#define EPS 0.05f

typedef __attribute__((ext_vector_type(8))) short bf16x8;
typedef __attribute__((ext_vector_type(4))) float f32x4;

__device__ __forceinline__ void async16(void* lds, const void* g) {
  __builtin_amdgcn_global_load_lds((const __attribute__((address_space(1))) void*)g,
                                   (__attribute__((address_space(3))) void*)lds, 16, 0, 0);
}

__device__ __forceinline__ unsigned pk_bf16(float a, float b) {
  unsigned ua = __float_as_uint(a); ua += 0x7FFFu + ((ua >> 16) & 1u);
  unsigned ub = __float_as_uint(b); ub += 0x7FFFu + ((ub >> 16) & 1u);
  return (ua >> 16) | (ub & 0xFFFF0000u);
}

// ---------- prep: row sum-sq (esq or inv2=2/norm) + bf16 (RTNE) conversion ----------
__global__ __launch_bounds__(256) void prep_kernel(const float* __restrict__ src,
                                                   short* __restrict__ dst16,
                                                   float* __restrict__ outv, int mode) {
  int r = blockIdx.x * 4 + (threadIdx.x >> 6);
  int lane = threadIdx.x & 63;
  const float4* row4 = (const float4*)(src + (size_t)r * DDIM);
  float4 v0 = row4[lane];
  float4 v1 = row4[lane + 64];
  uint2 p0, p1;
  p0.x = pk_bf16(v0.x, v0.y); p0.y = pk_bf16(v0.z, v0.w);
  p1.x = pk_bf16(v1.x, v1.y); p1.y = pk_bf16(v1.z, v1.w);
  *(uint2*)(dst16 + (size_t)r * DDIM + lane * 4) = p0;
  *(uint2*)(dst16 + (size_t)r * DDIM + 256 + lane * 4) = p1;
  float ss = v0.x*v0.x + v0.y*v0.y + v0.z*v0.z + v0.w*v0.w
           + v1.x*v1.x + v1.y*v1.y + v1.z*v1.z + v1.w*v1.w;
  #pragma unroll
  for (int off = 32; off; off >>= 1) ss += __shfl_down(ss, off);
  if (lane == 0) outv[r] = mode ? 2.0f / fmaxf(sqrtf(ss), 1e-12f) : ss;
}

// ---------- main pass: 256x256-tile 8-phase-style MFMA GEMM + per-block top-2 ----------
// Grid 2048 = 128 m-tiles x 16 n-tiles; 512 threads = 8 waves (2 M x 4 N),
// per-wave output 128x64, acc[8][4] f32x4. A and B stream through a
// double-buffered 128 KiB LDS (BK=64). Stage via global_load_lds with the
// proven both-sides chunk-XOR swizzle (source pre-swizzled (lane&7)^(lane>>3);
// read-side (kk*4+q)^(c16&7) -- same involution). Per K-tile: 4 phases of
// {ds_reads ; s_barrier ; setprio(1) ; 16 MFMA ; setprio(0) ; s_barrier},
// then STAGE(kt+2) + counted vmcnt(8) (never 0 until tail) + barrier --
// the r8-verified skeleton with phase-split compute (T3+T4+T5).
// XCD-contiguous block decode: each XCD gets 16 consecutive m-tiles x all
// n-tiles -> concurrent working set = 2 A-panels (1 MB) + 16 B K-slices
// (0.5 MB) per XCD L2. K-accumulation order identical to the proven r9
// kernel (same chunk->MFMA sequence) => bit-identical scores.
__global__ __launch_bounds__(512, 2) void vq_mm(const short* __restrict__ xb,
                                                const short* __restrict__ eb,
                                                const float* __restrict__ esq,
                                                const float* __restrict__ inv2,
                                                float4* __restrict__ top2g) {
  __shared__ __attribute__((aligned(16))) short As[2 * 256 * 64];  // 65536 B
  __shared__ __attribute__((aligned(16))) short Bs[2 * 256 * 64];  // 65536 B

  const int tid = threadIdx.x;
  const int lane = tid & 63;
  const int w = tid >> 6;          // 0..7
  const int wm = w >> 2;           // 0..1 : rows wm*128..+128
  const int wn = w & 3;            // 0..3 : cols wn*64..+64
  const int q = lane >> 4, c16 = lane & 15;

  // XCD-contiguous decode (2048 % 8 == 0 -> bijective)
  const int b = blockIdx.x;
  const int wg = (b & 7) * 256 + (b >> 3);
  const int ntile = wg & 15, mtile = wg >> 4;
  const int m0 = mtile * 256;
  const int n0c = ntile * 256;

  // ---- stage constants: instr i covers rows i*64 + w*8 + (lane>>3), phys
  // chunk lane&7 holds logical chunk (lane&7)^(lane>>3) (r&7 == lane>>3)
  const int lsw = (lane & 7) ^ (lane >> 3);
  const short* gA = xb + (size_t)(m0 + w * 8 + (lane >> 3)) * 512 + lsw * 8;
  const short* gB = eb + (size_t)(n0c + w * 8 + (lane >> 3)) * 512 + lsw * 8;

#define STAGE_A(kt) do { short* d_ = As + (((kt) & 1) << 14) + w * 512;      \
    const short* s_ = gA + (kt) * 64;                                        \
    _Pragma("unroll") for (int i_ = 0; i_ < 4; ++i_)                         \
      async16(d_ + i_ * 4096, s_ + (size_t)i_ * 32768); } while (0)
#define STAGE_B(kt) do { short* d_ = Bs + (((kt) & 1) << 14) + w * 512;      \
    const short* s_ = gB + (kt) * 64;                                        \
    _Pragma("unroll") for (int i_ = 0; i_ < 4; ++i_)                         \
      async16(d_ + i_ * 4096, s_ + (size_t)i_ * 32768); } while (0)

  // ---- fragment read constants (shorts) ----
  const int arow = (wm * 128 + c16) * 64;   // + ti*1024 + ck
  const int brow = (wn * 64 + c16) * 64;    // + tj*1024 + ck
  const int cxor = (c16 & 7);

  f32x4 acc[8][4];
  #pragma unroll
  for (int ti = 0; ti < 8; ++ti)
    #pragma unroll
    for (int tj = 0; tj < 4; ++tj) acc[ti][tj] = (f32x4){0.f, 0.f, 0.f, 0.f};

  // prologue: K-tiles 0,1 in flight; wait for tile 0's 8 loads only
  STAGE_A(0); STAGE_B(0);
  STAGE_A(1); STAGE_B(1);
  asm volatile("s_waitcnt vmcnt(8)" ::: "memory");
  asm volatile("s_barrier" ::: "memory");

  for (int kt = 0; kt < 8; ++kt) {
    const short* Ac = As + ((kt & 1) << 14) + arow;
    const short* Bc = Bs + ((kt & 1) << 14) + brow;
    #pragma unroll
    for (int kk = 0; kk < 2; ++kk) {
      const int ck = ((kk * 4 + q) ^ cxor) * 8;
      // ---- phase A: load af[0..7]+bf[0..1], mfma ti0-7 x tj0-1 ----
      bf16x8 af[8], bf[2];
      #pragma unroll
      for (int ti = 0; ti < 8; ++ti)
        af[ti] = *(const bf16x8*)(Ac + ti * 1024 + ck);
      #pragma unroll
      for (int tj = 0; tj < 2; ++tj)
        bf[tj] = *(const bf16x8*)(Bc + tj * 1024 + ck);
      asm volatile("s_barrier" ::: "memory");
      __builtin_amdgcn_s_setprio(1);
      #pragma unroll
      for (int ti = 0; ti < 8; ++ti)
        #pragma unroll
        for (int tj = 0; tj < 2; ++tj)
          acc[ti][tj] = __builtin_amdgcn_mfma_f32_16x16x32_bf16(af[ti], bf[tj], acc[ti][tj], 0, 0, 0);
      __builtin_amdgcn_s_setprio(0);
      asm volatile("s_barrier" ::: "memory");
      // ---- phase B: load bf[2..3], mfma ti0-7 x tj2-3 ----
      bf16x8 bg[2];
      #pragma unroll
      for (int tj = 0; tj < 2; ++tj)
        bg[tj] = *(const bf16x8*)(Bc + (tj + 2) * 1024 + ck);
      asm volatile("s_barrier" ::: "memory");
      __builtin_amdgcn_s_setprio(1);
      #pragma unroll
      for (int ti = 0; ti < 8; ++ti)
        #pragma unroll
        for (int tj = 0; tj < 2; ++tj)
          acc[ti][tj + 2] = __builtin_amdgcn_mfma_f32_16x16x32_bf16(af[ti], bg[tj], acc[ti][tj + 2], 0, 0, 0);
      __builtin_amdgcn_s_setprio(0);
      asm volatile("s_barrier" ::: "memory");
    }
    // stage K-tile kt+2 into the buffer just freed (all reads of buf kt&1
    // retired: post-MFMA barrier above). Counted wait: leave the newest 8
    // (STAGE(kt+2)) in flight; STAGE(kt+1) proven landed.
    if (kt <= 5) {
      STAGE_A(kt + 2); STAGE_B(kt + 2);
      asm volatile("s_waitcnt vmcnt(8)" ::: "memory");
    } else if (kt == 6) {
      asm volatile("s_waitcnt vmcnt(0)" ::: "memory");
    }
    asm volatile("s_barrier" ::: "memory");
  }
#undef STAGE_A
#undef STAGE_B

  // ---------- epilogue: scores + per-row top-2 over this block's 256 cols ----------
  __syncthreads();   // LDS reusable
  float* rS1 = (float*)As;            // [4][256]
  float* rS2 = rS1 + 1024;
  int*   rI1 = (int*)(rS2 + 1024);

  float nes[4];
  #pragma unroll
  for (int tj = 0; tj < 4; ++tj)
    nes[tj] = -esq[n0c + wn * 64 + tj * 16 + c16];

  #pragma unroll
  for (int ti = 0; ti < 8; ++ti) {
    const f32x4 iv4 = *(const f32x4*)&inv2[m0 + wm * 128 + ti * 16 + q * 4];
    #pragma unroll
    for (int r = 0; r < 4; ++r) {
      const float iv = iv4[r];
      float a1 = -3e38f, a2 = -3e38f; int ai = 0;
      #pragma unroll
      for (int tj = 0; tj < 4; ++tj) {
        float sc = fmaf(acc[ti][tj][r], iv, nes[tj]);
        float mn = fminf(sc, a1);
        a2 = fmaxf(a2, mn);
        if (sc > a1) { a1 = sc; ai = n0c + wn * 64 + tj * 16 + c16; }
      }
      #pragma unroll
      for (int off = 1; off < 16; off <<= 1) {
        float b1 = __shfl_xor(a1, off);
        float b2 = __shfl_xor(a2, off);
        int   bi = __shfl_xor(ai, off);
        float mn = fminf(a1, b1);
        a2 = fmaxf(fmaxf(a2, b2), mn);
        if (b1 > a1 || (b1 == a1 && bi < ai)) { a1 = b1; ai = bi; }
      }
      if (c16 == 0) {
        const int row = wm * 128 + ti * 16 + q * 4 + r;
        rS1[wn * 256 + row] = a1; rS2[wn * 256 + row] = a2; rI1[wn * 256 + row] = ai;
      }
    }
  }
  __syncthreads();
  if (tid < 256) {
    float a1 = rS1[tid], a2 = rS2[tid]; int ai = rI1[tid];
    #pragma unroll
    for (int g = 1; g < 4; ++g) {
      float b1 = rS1[g * 256 + tid], b2 = rS2[g * 256 + tid]; int bi = rI1[g * 256 + tid];
      float mn = fminf(a1, b1);
      a2 = fmaxf(fmaxf(a2, b2), mn);
      if (b1 > a1 || (b1 == a1 && bi < ai)) { a1 = b1; ai = bi; }
    }
    top2g[(size_t)ntile * NN + m0 + tid] = make_float4(a1, __int_as_float(ai), a2, 0.f);
  }
}

// ---------- finalize: merge 16 n-tile partials, write idx, flag small margins ----------
__global__ __launch_bounds__(256) void finalize_kernel(const float4* __restrict__ top2g,
                                                       float* __restrict__ out_ind,
                                                       int* __restrict__ flags,
                                                       int* __restrict__ list,
                                                       int* __restrict__ cnt) {
  int row = blockIdx.x * 256 + threadIdx.x;
  float a1 = -3e38f, a2 = -3e38f; int ai = 0;
  #pragma unroll
  for (int kq = 0; kq < 16; ++kq) {
    float4 t = top2g[(size_t)kq * NN + row];
    float b1 = t.x, b2 = t.z; int bi = __float_as_int(t.y);
    float mn = fminf(a1, b1);
    a2 = fmaxf(fmaxf(a2, b2), mn);
    if (b1 > a1 || (b1 == a1 && bi < ai)) { a1 = b1; ai = bi; }
  }
  out_ind[row] = (float)ai;
  if (a1 - a2 < EPS) {
    int p = atomicAdd(cnt, 1);
    list[p] = row;
    flags[row] = p + 1;
  } else {
    flags[row] = 0;
  }
}

// ---------- cleanup: exact fp32 rescore of flagged rows (proven r9 version) ----------
__global__ __launch_bounds__(256) void cleanup_kernel(const float* __restrict__ x,
                                                      const float* __restrict__ embed,
                                                      const float* __restrict__ esq,
                                                      const float* __restrict__ inv2,
                                                      const int* __restrict__ list,
                                                      const int* __restrict__ cnt,
                                                      float2* __restrict__ exact) {
  __shared__ float xr[DDIM];
  __shared__ float red_s[4];
  __shared__ int   red_i[4];
  const int rs = blockIdx.x & 31, kc = blockIdx.x >> 5;
  const int tid = threadIdx.x;
  const int lane = tid & 63, wid = tid >> 6;
  const int n = *cnt;
  for (int ii = rs; ii < n; ii += 32) {
    const int row = list[ii];
    __syncthreads();
    if (tid < 128) *(float4*)&xr[tid * 4] = *(const float4*)&x[(size_t)row * DDIM + tid * 4];
    __syncthreads();
    const float iv = inv2[row];
    float bs = -3e38f; int bi = 0;
    for (int cc = 0; cc < 2; ++cc) {
      const int code = kc * 512 + cc * 256 + tid;
      const float4* er = (const float4*)&embed[(size_t)code * DDIM];
      float acc = 0.f;
      for (int d = 0; d < DDIM / 4; ++d) {
        float4 e4 = er[d];
        float4 x4 = *(const float4*)&xr[d * 4];
        acc += x4.x * e4.x + x4.y * e4.y + x4.z * e4.z + x4.w * e4.w;
      }
      float sc = fmaf(acc, iv, -esq[code]);
      if (sc > bs || (sc == bs && code < bi)) { bs = sc; bi = code; }
    }
    #pragma unroll
    for (int off = 1; off < 64; off <<= 1) {
      float b1 = __shfl_xor(bs, off);
      int   b2 = __shfl_xor(bi, off);
      if (b1 > bs || (b1 == bs && b2 < bi)) { bs = b1; bi = b2; }
    }
    if (lane == 0) { red_s[wid] = bs; red_i[wid] = bi; }
    __syncthreads();
    if (tid == 0) {
      for (int ww = 1; ww < 4; ++ww)
        if (red_s[ww] > red_s[0] || (red_s[ww] == red_s[0] && red_i[ww] < red_i[0])) {
          red_s[0] = red_s[ww]; red_i[0] = red_i[ww];
        }
      exact[(size_t)ii * 8 + kc] = make_float2(red_s[0], (float)red_i[0]);
    }
  }
}

// ---------- gather + transpose (merges exact results for flagged rows) ----------
__global__ __launch_bounds__(256) void gather_kernel(const float* __restrict__ embed,
                                                     const int* __restrict__ flags,
                                                     const float2* __restrict__ exact,
                                                     float* __restrict__ out_ind,
                                                     float* __restrict__ out_q) {
  __shared__ int lidx[64];
  __shared__ float trans[64 * 65];
  const int n0 = blockIdx.x * 64;
  const int tid = threadIdx.x;
  if (tid < 64) {
    const int row = n0 + tid;
    const int f = flags[row];
    int idx;
    if (f) {
      float bsv = -3e38f; int bi = 0;
      const float2* e8 = &exact[(size_t)(f - 1) * 8];
      #pragma unroll
      for (int k = 0; k < 8; ++k) {
        float2 t = e8[k];
        int ci = (int)t.y;
        if (t.x > bsv || (t.x == bsv && ci < bi)) { bsv = t.x; bi = ci; }
      }
      idx = bi;
      out_ind[row] = (float)idx;
    } else {
      idx = (int)out_ind[row];
    }
    lidx[tid] = idx;
  }
  __syncthreads();
  const int bb = n0 >> 12;
  const int t0 = n0 & (TT - 1);
  const int w = tid >> 6, lane = tid & 63;
  for (int d0 = 0; d0 < DDIM; d0 += 64) {
    if (d0) __syncthreads();
    #pragma unroll
    for (int qq = 0; qq < 16; ++qq) {
      int tt2 = w * 16 + qq;
      int e = lidx[tt2];
      trans[lane * 65 + tt2] = embed[(size_t)e * DDIM + d0 + lane];
    }
    __syncthreads();
    #pragma unroll
    for (int qq = 0; qq < 4; ++qq) {
      int dl = (tid >> 4) * 4 + qq;
      int t4 = (tid & 15) * 4;
      float4 o;
      o.x = trans[dl * 65 + t4 + 0];
      o.y = trans[dl * 65 + t4 + 1];
      o.z = trans[dl * 65 + t4 + 2];
      o.w = trans[dl * 65 + t4 + 3];
      *(float4*)&out_q[((size_t)bb * DDIM + d0 + dl) * TT + t0 + t4] = o;
    }
  }
}

extern "C" void kernel_launch(void* const* d_in, const int* in_sizes, int n_in,
                              void* d_out, int out_size, void* d_ws, size_t ws_size,
                              hipStream_t stream) {
  const float* x     = (const float*)d_in[0];
  const float* embed = (const float*)d_in[1];
  char* ws = (char*)d_ws;
  short* xb      = (short*)(ws);                         // 33,554,432 B
  short* eb      = (short*)(ws + 33554432);              //  4,194,304 B
  float* esq     = (float*)(ws + 37748736);              //     16,384 B
  float* inv2    = (float*)(ws + 37765120);              //    131,072 B
  int* list      = (int*)(ws + 39993344);                //    131,072 B
  int* flags     = (int*)(ws + 40124416);                //    131,072 B
  float2* exact  = (float2*)(ws + 40255488);             //  2,097,152 B
  int* cnt       = (int*)(ws + 42352640);                //          4 B

  float* out_ind = (float*)d_out;
  float* out_q   = out_ind + NN;
  // out_q (64 MB, written only by gather at the end) doubles as scratch for
  // the 16 per-n-tile top-2 partials (8 MB) between vq_mm and finalize.
  float4* top2g  = (float4*)out_q;

  prep_kernel<<<KK / 4, 256, 0, stream>>>(embed, eb, esq, 0);
  prep_kernel<<<NN / 4, 256, 0, stream>>>(x, xb, inv2, 1);
  hipMemsetAsync(cnt, 0, 4, stream);
  vq_mm<<<2048, 512, 0, stream>>>(xb, eb, esq, inv2, top2g);
  finalize_kernel<<<NN / 256, 256, 0, stream>>>(top2g, out_ind, flags, list, cnt);
  cleanup_kernel<<<256, 256, 0, stream>>>(x, embed, esq, inv2, list, cnt, exact);
  gather_kernel<<<NN / 64, 256, 0, stream>>>(embed, flags, exact, out_ind, out_q);
}

// Round 15
// 316.165 us; speedup vs baseline: 1.3568x; 1.3568x over previous
//
#include <hip/hip_runtime.h>
#include <math.h>

#define BB 8
#define TT 4096
#define DDIM 512
#define KK 4096
#define NN (BB*TT)
#define EPS 0.05f

typedef __attribute__((ext_vector_type(8))) short bf16x8;
typedef __attribute__((ext_vector_type(4))) float f32x4;

__device__ __forceinline__ void async16(void* lds, const void* g) {
  __builtin_amdgcn_global_load_lds((const __attribute__((address_space(1))) void*)g,
                                   (__attribute__((address_space(3))) void*)lds, 16, 0, 0);
}

__device__ __forceinline__ unsigned pk_bf16(float a, float b) {
  unsigned ua = __float_as_uint(a); ua += 0x7FFFu + ((ua >> 16) & 1u);
  unsigned ub = __float_as_uint(b); ub += 0x7FFFu + ((ub >> 16) & 1u);
  return (ua >> 16) | (ub & 0xFFFF0000u);
}

// ---------- prep (embed only): row sum-sq + bf16 (RTNE) conversion ----------
__global__ __launch_bounds__(256) void prep_kernel(const float* __restrict__ src,
                                                   short* __restrict__ dst16,
                                                   float* __restrict__ outv, int mode) {
  int r = blockIdx.x * 4 + (threadIdx.x >> 6);
  int lane = threadIdx.x & 63;
  const float4* row4 = (const float4*)(src + (size_t)r * DDIM);
  float4 v0 = row4[lane];
  float4 v1 = row4[lane + 64];
  uint2 p0, p1;
  p0.x = pk_bf16(v0.x, v0.y); p0.y = pk_bf16(v0.z, v0.w);
  p1.x = pk_bf16(v1.x, v1.y); p1.y = pk_bf16(v1.z, v1.w);
  *(uint2*)(dst16 + (size_t)r * DDIM + lane * 4) = p0;
  *(uint2*)(dst16 + (size_t)r * DDIM + 256 + lane * 4) = p1;
  float ss = v0.x*v0.x + v0.y*v0.y + v0.z*v0.z + v0.w*v0.w
           + v1.x*v1.x + v1.y*v1.y + v1.z*v1.z + v1.w*v1.w;
  #pragma unroll
  for (int off = 32; off; off >>= 1) ss += __shfl_down(ss, off);
  if (lane == 0) outv[r] = mode ? 2.0f / fmaxf(sqrtf(ss), 1e-12f) : ss;
}

// ---------- main MFMA pass: fused x-prep + counted-vmcnt loop (r9) ----------
// NEW vs r9 (only change): A-tile swizzle extended by one bit to kill the
// measured 2-way bank conflict. Derivation: A-read lanes c16 and c16+8 read
// rows 8 apart (row stride 1024 B = 0 mod 128 B) with identical chunk-XOR
// (c16&7) -> same bank on every ds_read_b128 (SQ_LDS_BANK_CONFLICT = 2^23,
// exactly 2 cyc/read). Fix (both-sides involution, rule #21):
//   write: phys chunk = c ^ (rl&7) ^ (((rl>>3)&1)<<2)
//   read:  ach XOR mask = (c16&7) ^ ((c16>>3)<<2)
// (read row = wr*64+ti*16+c16 -> (row>>3)&1 == c16>>3, consistent). Bijective
// per row; A is written by ds_write only (no DMA-linearity constraint).
__global__ __launch_bounds__(512, 2) void vq_mfma(const float* __restrict__ xf,
                                                  const short* __restrict__ eb,
                                                  const float* __restrict__ esq,
                                                  float* __restrict__ inv2g,
                                                  float* __restrict__ out_ind,
                                                  int* __restrict__ flags,
                                                  int* __restrict__ list,
                                                  int* __restrict__ cnt) {
  __shared__ __attribute__((aligned(16))) short As[128 * 512];    // 131072 B
  __shared__ __attribute__((aligned(16))) short Bs[2 * 256 * 32]; //  32768 B

  const int tid = threadIdx.x;
  const int lane = tid & 63;
  const int w = tid >> 6;          // 0..7
  const int wr = w >> 2;           // row half (0..1): rows wr*64..+64
  const int wc = w & 3;            // code quarter within 256-tile
  const int q = lane >> 4, c16 = lane & 15;
  const int n0 = blockIdx.x * 128;

  // ---- fused A prep: wave w converts rows w*16 .. w*16+15 ----
  #pragma unroll 2
  for (int j = 0; j < 16; ++j) {
    const int rl = w * 16 + j;       // local row 0..127
    const float4* row4 = (const float4*)(xf + (size_t)(n0 + rl) * DDIM);
    float4 v0 = row4[lane];
    float4 v1 = row4[lane + 64];
    uint2 p0, p1;
    p0.x = pk_bf16(v0.x, v0.y); p0.y = pk_bf16(v0.z, v0.w);
    p1.x = pk_bf16(v1.x, v1.y); p1.y = pk_bf16(v1.z, v1.w);
    // ds_write with extended chunk swizzle (see header comment)
    const int rx = (rl & 7) ^ (((rl >> 3) & 1) << 2);
    char* rowbase = (char*)(As + rl * 512);
    *(uint2*)(rowbase + ((((lane >> 1)     ) ^ rx) * 16 + (lane & 1) * 8)) = p0;
    *(uint2*)(rowbase + ((((lane >> 1) + 32) ^ rx) * 16 + (lane & 1) * 8)) = p1;
    // identical summation + reduction order as old prep => bit-identical inv2
    float ss = v0.x*v0.x + v0.y*v0.y + v0.z*v0.z + v0.w*v0.w
             + v1.x*v1.x + v1.y*v1.y + v1.z*v1.z + v1.w*v1.w;
    #pragma unroll
    for (int off = 32; off; off >>= 1) ss += __shfl_down(ss, off);
    if (lane == 0) {
      float inv = 2.0f / fmaxf(sqrtf(ss), 1e-12f);
      ((float*)Bs)[rl] = inv;        // park for epilogue (pre-STAGE)
      inv2g[n0 + rl] = inv;          // for cleanup kernel
    }
  }
  __syncthreads();                   // A writes + parked inv2 visible

  f32x4 iv4[4];
  #pragma unroll
  for (int ti = 0; ti < 4; ++ti)
    iv4[ti] = *(const f32x4*)&((const float*)Bs)[wr * 64 + ti * 16 + q * 4];
  __syncthreads();                   // everyone has iv4; Bs reusable

  // ---- B stage thread constants (pair-window swizzle) ----
  const int x = (lane & 7) ^ (lane >> 3);
  const int scode = w * 16 + (lane >> 3) * 2 + (x >> 2);   // k=0 local code
  const short* gB = eb + (size_t)scode * 512 + (x & 3) * 8;

#define STAGE(gn) do {                                                     \
    const short* src_ = gB + (size_t)((gn) >> 4) * (256 * 512) + ((gn) & 15) * 32; \
    short* dst_ = Bs + (((gn) & 1) << 13) + w * 512;                       \
    async16(dst_,        src_);                                            \
    async16(dst_ + 4096, src_ + 128 * 512); } while (0)

  STAGE(0);
  STAGE(1);

  const int sigB8 = ((((c16 & 1) << 2) | q) ^ ((c16 >> 1) & 7)) * 8;
  const int brow0 = (wc * 32 + (c16 >> 1)) * 64 + sigB8;    // + tj*512 + buf*8192
  const int arow0 = (wr * 64 + c16) * 512;                  // + ti*8192 + ach
  const int amask = (c16 & 7) ^ ((c16 >> 3) << 2);          // conflict-free A XOR

  float s1[16], s2v[16];
  int   i1[16];
  #pragma unroll
  for (int s = 0; s < 16; ++s) { s1[s] = -3e38f; s2v[s] = -3e38f; i1[s] = 0; }

  asm volatile("s_waitcnt vmcnt(2)" ::: "memory");
  asm volatile("s_barrier" ::: "memory");

  for (int ct = 0; ct < 16; ++ct) {
    float nes[4];
    #pragma unroll
    for (int tj = 0; tj < 4; ++tj)
      nes[tj] = -esq[ct * 256 + wc * 64 + tj * 16 + c16];
    f32x4 acc[4][4];
    #pragma unroll
    for (int ti = 0; ti < 4; ++ti)
      #pragma unroll
      for (int tj = 0; tj < 4; ++tj) acc[ti][tj] = (f32x4){0.f, 0.f, 0.f, 0.f};

    #pragma unroll 2
    for (int s = 0; s < 16; ++s) {
      const int g = ct * 16 + s;
      const short* Ap = As + arow0;
      const short* Bp = Bs + ((g & 1) << 13) + brow0;
      const int ach = ((s * 4 + q) ^ amask) * 8;
      bf16x8 af[4], bf[4];
      #pragma unroll
      for (int ti = 0; ti < 4; ++ti)
        af[ti] = *(const bf16x8*)(Ap + ti * 8192 + ach);
      #pragma unroll
      for (int tj = 0; tj < 4; ++tj)
        bf[tj] = *(const bf16x8*)(Bp + tj * 512);
      __builtin_amdgcn_s_setprio(1);
      #pragma unroll
      for (int ti = 0; ti < 4; ++ti)
        #pragma unroll
        for (int tj = 0; tj < 4; ++tj)
          acc[ti][tj] = __builtin_amdgcn_mfma_f32_16x16x32_bf16(af[ti], bf[tj], acc[ti][tj], 0, 0, 0);
      __builtin_amdgcn_s_setprio(0);
      asm volatile("s_barrier" ::: "memory");   // all waves consumed buf g&1
      if (g <= 253) {
        STAGE(g + 2);
        asm volatile("s_waitcnt vmcnt(2)" ::: "memory");  // STAGE(g+1) landed
      } else if (g == 254) {
        asm volatile("s_waitcnt vmcnt(0)" ::: "memory");
      }
      asm volatile("s_barrier" ::: "memory");   // buf (g+1)&1 readable
    }

    const int colbase = ct * 256 + wc * 64 + c16;
    #pragma unroll
    for (int ti = 0; ti < 4; ++ti)
      #pragma unroll
      for (int r = 0; r < 4; ++r) {
        const int slot = ti * 4 + r;
        const float iv = iv4[ti][r];
        #pragma unroll
        for (int tj = 0; tj < 4; ++tj) {
          float sc = fmaf(acc[ti][tj][r], iv, nes[tj]);
          float mn = fminf(sc, s1[slot]);
          s2v[slot] = fmaxf(s2v[slot], mn);
          if (sc > s1[slot]) { s1[slot] = sc; i1[slot] = colbase + tj * 16; }
        }
      }
  }
#undef STAGE

  __syncthreads();
  float* rS1 = (float*)Bs;           // [4][128]
  float* rS2 = rS1 + 512;
  int*   rI1 = (int*)(rS2 + 512);
  #pragma unroll
  for (int slot = 0; slot < 16; ++slot) {
    float a1 = s1[slot], a2 = s2v[slot]; int ai = i1[slot];
    #pragma unroll
    for (int off = 1; off < 16; off <<= 1) {
      float b1 = __shfl_xor(a1, off);
      float b2 = __shfl_xor(a2, off);
      int   bi = __shfl_xor(ai, off);
      float mn = fminf(a1, b1);
      a2 = fmaxf(fmaxf(a2, b2), mn);
      if (b1 > a1 || (b1 == a1 && bi < ai)) { a1 = b1; ai = bi; }
    }
    if (c16 == 0) {
      int row = wr * 64 + (slot >> 2) * 16 + q * 4 + (slot & 3);
      rS1[wc * 128 + row] = a1; rS2[wc * 128 + row] = a2; rI1[wc * 128 + row] = ai;
    }
  }
  __syncthreads();
  if (tid < 128) {
    float a1 = rS1[tid], a2 = rS2[tid]; int ai = rI1[tid];
    #pragma unroll
    for (int gq = 1; gq < 4; ++gq) {
      float b1 = rS1[gq * 128 + tid], b2 = rS2[gq * 128 + tid]; int bi = rI1[gq * 128 + tid];
      float mn = fminf(a1, b1);
      a2 = fmaxf(fmaxf(a2, b2), mn);
      if (b1 > a1 || (b1 == a1 && bi < ai)) { a1 = b1; ai = bi; }
    }
    const int row = n0 + tid;
    out_ind[row] = (float)ai;
    if (a1 - a2 < EPS) {
      int p = atomicAdd(cnt, 1);
      list[p] = row;
      flags[row] = p + 1;
    } else {
      flags[row] = 0;
    }
  }
}

// ---------- cleanup: exact fp32 rescore of flagged rows (proven r9 version) ----------
__global__ __launch_bounds__(256) void cleanup_kernel(const float* __restrict__ x,
                                                      const float* __restrict__ embed,
                                                      const float* __restrict__ esq,
                                                      const float* __restrict__ inv2,
                                                      const int* __restrict__ list,
                                                      const int* __restrict__ cnt,
                                                      float2* __restrict__ exact) {
  __shared__ float xr[DDIM];
  __shared__ float red_s[4];
  __shared__ int   red_i[4];
  const int rs = blockIdx.x & 31, kc = blockIdx.x >> 5;
  const int tid = threadIdx.x;
  const int lane = tid & 63, wid = tid >> 6;
  const int n = *cnt;
  for (int ii = rs; ii < n; ii += 32) {
    const int row = list[ii];
    __syncthreads();
    if (tid < 128) *(float4*)&xr[tid * 4] = *(const float4*)&x[(size_t)row * DDIM + tid * 4];
    __syncthreads();
    const float iv = inv2[row];
    float bs = -3e38f; int bi = 0;
    for (int cc = 0; cc < 2; ++cc) {
      const int code = kc * 512 + cc * 256 + tid;
      const float4* er = (const float4*)&embed[(size_t)code * DDIM];
      float acc = 0.f;
      for (int d = 0; d < DDIM / 4; ++d) {
        float4 e4 = er[d];
        float4 x4 = *(const float4*)&xr[d * 4];
        acc += x4.x * e4.x + x4.y * e4.y + x4.z * e4.z + x4.w * e4.w;
      }
      float sc = fmaf(acc, iv, -esq[code]);
      if (sc > bs || (sc == bs && code < bi)) { bs = sc; bi = code; }
    }
    #pragma unroll
    for (int off = 1; off < 64; off <<= 1) {
      float b1 = __shfl_xor(bs, off);
      int   b2 = __shfl_xor(bi, off);
      if (b1 > bs || (b1 == bs && b2 < bi)) { bs = b1; bi = b2; }
    }
    if (lane == 0) { red_s[wid] = bs; red_i[wid] = bi; }
    __syncthreads();
    if (tid == 0) {
      for (int ww = 1; ww < 4; ++ww)
        if (red_s[ww] > red_s[0] || (red_s[ww] == red_s[0] && red_i[ww] < red_i[0])) {
          red_s[0] = red_s[ww]; red_i[0] = red_i[ww];
        }
      exact[(size_t)ii * 8 + kc] = make_float2(red_s[0], (float)red_i[0]);
    }
  }
}

// ---------- gather + transpose (merges exact results for flagged rows) ----------
__global__ __launch_bounds__(256) void gather_kernel(const float* __restrict__ embed,
                                                     const int* __restrict__ flags,
                                                     const float2* __restrict__ exact,
                                                     float* __restrict__ out_ind,
                                                     float* __restrict__ out_q) {
  __shared__ int lidx[64];
  __shared__ float trans[64 * 65];
  const int n0 = blockIdx.x * 64;
  const int tid = threadIdx.x;
  if (tid < 64) {
    const int row = n0 + tid;
    const int f = flags[row];
    int idx;
    if (f) {
      float bsv = -3e38f; int bi = 0;
      const float2* e8 = &exact[(size_t)(f - 1) * 8];
      #pragma unroll
      for (int k = 0; k < 8; ++k) {
        float2 t = e8[k];
        int ci = (int)t.y;
        if (t.x > bsv || (t.x == bsv && ci < bi)) { bsv = t.x; bi = ci; }
      }
      idx = bi;
      out_ind[row] = (float)idx;
    } else {
      idx = (int)out_ind[row];
    }
    lidx[tid] = idx;
  }
  __syncthreads();
  const int bb = n0 >> 12;
  const int t0 = n0 & (TT - 1);
  const int w = tid >> 6, lane = tid & 63;
  for (int d0 = 0; d0 < DDIM; d0 += 64) {
    if (d0) __syncthreads();
    #pragma unroll
    for (int qq = 0; qq < 16; ++qq) {
      int tt2 = w * 16 + qq;
      int e = lidx[tt2];
      trans[lane * 65 + tt2] = embed[(size_t)e * DDIM + d0 + lane];
    }
    __syncthreads();
    #pragma unroll
    for (int qq = 0; qq < 4; ++qq) {
      int dl = (tid >> 4) * 4 + qq;
      int t4 = (tid & 15) * 4;
      float4 o;
      o.x = trans[dl * 65 + t4 + 0];
      o.y = trans[dl * 65 + t4 + 1];
      o.z = trans[dl * 65 + t4 + 2];
      o.w = trans[dl * 65 + t4 + 3];
      *(float4*)&out_q[((size_t)bb * DDIM + d0 + dl) * TT + t0 + t4] = o;
    }
  }
}

extern "C" void kernel_launch(void* const* d_in, const int* in_sizes, int n_in,
                              void* d_out, int out_size, void* d_ws, size_t ws_size,
                              hipStream_t stream) {
  const float* x     = (const float*)d_in[0];
  const float* embed = (const float*)d_in[1];
  char* ws = (char*)d_ws;
  short* eb      = (short*)(ws + 33554432);              //  4,194,304 B
  float* esq     = (float*)(ws + 37748736);              //     16,384 B
  float* inv2    = (float*)(ws + 37765120);              //    131,072 B
  int* list      = (int*)(ws + 39993344);                //    131,072 B
  int* flags     = (int*)(ws + 40124416);                //    131,072 B
  float2* exact  = (float2*)(ws + 40255488);             //  2,097,152 B
  int* cnt       = (int*)(ws + 42352640);                //          4 B

  float* out_ind = (float*)d_out;
  float* out_q   = out_ind + NN;

  prep_kernel<<<KK / 4, 256, 0, stream>>>(embed, eb, esq, 0);
  hipMemsetAsync(cnt, 0, 4, stream);
  vq_mfma<<<256, 512, 0, stream>>>(x, eb, esq, inv2, out_ind, flags, list, cnt);
  cleanup_kernel<<<256, 256, 0, stream>>>(x, embed, esq, inv2, list, cnt, exact);
  gather_kernel<<<NN / 64, 256, 0, stream>>>(embed, flags, exact, out_ind, out_q);
}